// Round 1
// baseline (3352.095 us; speedup 1.0000x reference)
//
#include <hip/hip_runtime.h>
#include <math.h>

// Problem constants
constexpr int Bc = 8, Tc = 256, Dc = 512, Mc = 128, Lc = 4, Vc = 32000;
constexpr int Rc = Bc * Tc;          // 2048 rows
constexpr int Hc = 4 * Dc;           // 2048 hidden

#define DEV __device__ __forceinline__

DEV float wred64(float x) {
#pragma unroll
  for (int o = 32; o; o >>= 1) x += __shfl_xor(x, o);
  return x;
}

// ---------------------------------------------------------------- gather: x = center[idx]
__global__ __launch_bounds__(128) void gather_k(const int* __restrict__ idx,
                                                const float* __restrict__ center,
                                                float* __restrict__ x) {
  int r = blockIdx.x;
  int t = threadIdx.x;
  int id = idx[r];
  const float4* src = (const float4*)(center + (size_t)id * Dc);
  float4* dst = (float4*)(x + (size_t)r * Dc);
  dst[t] = src[t];
}

// ---------------------------------------------------------------- LayerNorm (row of 512)
__global__ __launch_bounds__(64) void ln_k(const float* __restrict__ in,
                                           const float* __restrict__ g,
                                           const float* __restrict__ b,
                                           float* __restrict__ out) {
  int r = blockIdx.x, t = threadIdx.x;
  const float4* row = (const float4*)(in + (size_t)r * Dc);
  float xv[8];
  *(float4*)&xv[0] = row[2 * t];
  *(float4*)&xv[4] = row[2 * t + 1];
  float s = 0.f, ss = 0.f;
#pragma unroll
  for (int e = 0; e < 8; ++e) { s += xv[e]; ss += xv[e] * xv[e]; }
  s = wred64(s); ss = wred64(ss);
  float mu = s * (1.f / Dc);
  float var = ss * (1.f / Dc) - mu * mu;
  float inv = 1.f / sqrtf(var + 1e-5f);
  float gg[8], bb[8], oo[8];
  *(float4*)&gg[0] = ((const float4*)g)[2 * t];
  *(float4*)&gg[4] = ((const float4*)g)[2 * t + 1];
  *(float4*)&bb[0] = ((const float4*)b)[2 * t];
  *(float4*)&bb[4] = ((const float4*)b)[2 * t + 1];
#pragma unroll
  for (int e = 0; e < 8; ++e) oo[e] = (xv[e] - mu) * inv * gg[e] + bb[e];
  float4* orow = (float4*)(out + (size_t)r * Dc);
  orow[2 * t] = *(float4*)&oo[0];
  orow[2 * t + 1] = *(float4*)&oo[4];
}

// ---------------------------------------------------------------- gw/gf GEMV + sigmoid
__global__ __launch_bounds__(64) void gwgf_k(const float* __restrict__ xn,
                                             const float* __restrict__ wgw, const float* __restrict__ bgw,
                                             const float* __restrict__ wgf, const float* __restrict__ bgf,
                                             float* __restrict__ gw, float* __restrict__ gf) {
  int r = blockIdx.x, t = threadIdx.x;
  const float4* row = (const float4*)(xn + (size_t)r * Dc);
  const float4* ww = (const float4*)wgw;
  const float4* wf = (const float4*)wgf;
  float dw = 0.f, df = 0.f;
#pragma unroll
  for (int j = 0; j < 2; ++j) {
    float xv[4], av[4], cv[4];
    *(float4*)xv = row[2 * t + j];
    *(float4*)av = ww[2 * t + j];
    *(float4*)cv = wf[2 * t + j];
#pragma unroll
    for (int e = 0; e < 4; ++e) { dw = fmaf(xv[e], av[e], dw); df = fmaf(xv[e], cv[e], df); }
  }
  dw = wred64(dw); df = wred64(df);
  if (t == 0) {
    gw[r] = 1.f / (1.f + expf(-(dw + bgw[0])));
    gf[r] = 0.9f / (1.f + expf(-(df + bgf[0])));
  }
}

// ---------------------------------------------------------------- l2 normalize rows of 128
__global__ __launch_bounds__(64) void l2n_k(float* __restrict__ p) {
  int r = blockIdx.x, t = threadIdx.x;
  float a = p[(size_t)r * Mc + t];
  float c = p[(size_t)r * Mc + 64 + t];
  float ss = wred64(a * a + c * c);
  float n = fmaxf(sqrtf(ss), 1e-12f);
  p[(size_t)r * Mc + t] = a / n;
  p[(size_t)r * Mc + 64 + t] = c / n;
}

// ---------------------------------------------------------------- fp32 tiled GEMM: C = act(A@B^T + bias)[*scale][+C]
// A [N,K] row-major, B [Mo,K] row-major, C [N,ldc]
enum { ACT_NONE = 0, ACT_TANH = 1, ACT_GELU = 2 };

template <int ACT, bool ACCUM, bool SCALE>
__global__ __launch_bounds__(256) void gemm_nt(const float* __restrict__ A,
                                               const float* __restrict__ B,
                                               float* __restrict__ C,
                                               const float* __restrict__ bias,
                                               int K, int ldc,
                                               const float* __restrict__ scale_ptr,
                                               float scale_const) {
  __shared__ float As[16][68];
  __shared__ float Bs[16][68];
  const int bm = blockIdx.y * 64, bn = blockIdx.x * 64;
  const int tid = threadIdx.x;
  const int ar = tid >> 2;            // 0..63
  const int ac = (tid & 3) * 4;       // 0,4,8,12
  const int tm = (tid >> 4) << 2;     // 0..60
  const int tn = (tid & 15) << 2;     // 0..60
  float acc[4][4] = {};
  for (int k0 = 0; k0 < K; k0 += 16) {
    float4 av = *(const float4*)(A + (size_t)(bm + ar) * K + k0 + ac);
    float4 bv = *(const float4*)(B + (size_t)(bn + ar) * K + k0 + ac);
    As[ac + 0][ar] = av.x; As[ac + 1][ar] = av.y; As[ac + 2][ar] = av.z; As[ac + 3][ar] = av.w;
    Bs[ac + 0][ar] = bv.x; Bs[ac + 1][ar] = bv.y; Bs[ac + 2][ar] = bv.z; Bs[ac + 3][ar] = bv.w;
    __syncthreads();
#pragma unroll
    for (int kk = 0; kk < 16; ++kk) {
      float a4[4], b4[4];
      *(float4*)a4 = *(const float4*)&As[kk][tm];
      *(float4*)b4 = *(const float4*)&Bs[kk][tn];
#pragma unroll
      for (int i = 0; i < 4; ++i)
#pragma unroll
        for (int j = 0; j < 4; ++j) acc[i][j] = fmaf(a4[i], b4[j], acc[i][j]);
    }
    __syncthreads();
  }
  float sc = 1.f;
  if (SCALE) sc = scale_const * (scale_ptr ? scale_ptr[0] : 1.f);
#pragma unroll
  for (int i = 0; i < 4; ++i) {
    int row = bm + tm + i;
#pragma unroll
    for (int j = 0; j < 4; ++j) {
      int col = bn + tn + j;
      float val = acc[i][j];
      if (bias) val += bias[col];
      if (ACT == ACT_TANH) val = tanhf(val);
      else if (ACT == ACT_GELU) val = 0.5f * val * (1.f + erff(val * 0.70710678118654752f));
      if (SCALE) val *= sc;
      float* cp = C + (size_t)row * ldc + col;
      if (ACCUM) val += *cp;
      *cp = val;
    }
  }
}

// ---------------------------------------------------------------- sequential memory scan
// one block per batch; thread (i,half) owns mem[i][half*64 .. +63] in registers
__global__ __launch_bounds__(256) void scan_k(const float* __restrict__ kp,
                                              const float* __restrict__ qp,
                                              const float* __restrict__ vp,
                                              const float* __restrict__ gwp,
                                              const float* __restrict__ gfp,
                                              float* __restrict__ reads,
                                              float* __restrict__ state_out) {
  int b = blockIdx.x, tid = threadIdx.x;
  int i = tid >> 1, half = tid & 1, jb = half << 6;
  float mem[64];
#pragma unroll
  for (int j = 0; j < 64; ++j) mem[j] = 0.f;
  __shared__ float sk[128], sq[128], sv[128], sread[128];
  for (int t = 0; t < Tc; ++t) {
    int r = b * Tc + t;
    if (tid < 128) {
      sk[tid] = kp[(size_t)r * Mc + tid];
      sv[tid] = vp[(size_t)r * Mc + tid];
    } else {
      sq[tid - 128] = qp[(size_t)r * Mc + tid - 128];
    }
    __syncthreads();
    // readout BEFORE update
    float acc = 0.f;
#pragma unroll
    for (int j = 0; j < 64; ++j) acc = fmaf(mem[j], sq[jb + j], acc);
    acc += __shfl_xor(acc, 1);
    if (!half) sread[i] = acc;
    // update
    float gwt = gwp[r], gft = gfp[r];
    float cvi = gwt * sv[i];
#pragma unroll
    for (int j = 0; j < 64; ++j) mem[j] = fmaf(gft, mem[j], cvi * sk[jb + j]);
    __syncthreads();
    if (tid < 128) reads[(size_t)r * Mc + tid] = sread[tid];
  }
#pragma unroll
  for (int j = 0; j < 64; ++j) state_out[((size_t)b * Mc + i) * Mc + jb + j] = mem[j];
}

// ---------------------------------------------------------------- launcher
extern "C" void kernel_launch(void* const* d_in, const int* in_sizes, int n_in,
                              void* d_out, int out_size, void* d_ws, size_t ws_size,
                              hipStream_t stream) {
  const int* idx = (const int*)d_in[0];
  const float* center = (const float*)d_in[1];
  // d_in[2] offset: dead code (x = (b_min+b_max)/2 = center)
  const float* wk = (const float*)d_in[3];
  const float* bk = (const float*)d_in[4];
  const float* wq = (const float*)d_in[5];
  const float* bq = (const float*)d_in[6];
  const float* wv = (const float*)d_in[7];
  const float* bv = (const float*)d_in[8];
  const float* wo = (const float*)d_in[9];
  const float* bo = (const float*)d_in[10];
  const float* wgw = (const float*)d_in[11];
  const float* bgw = (const float*)d_in[12];
  const float* wgf = (const float*)d_in[13];
  const float* bgf = (const float*)d_in[14];
  const float* ln1_g = (const float*)d_in[15];
  const float* ln1_b = (const float*)d_in[16];
  const float* ln2_g = (const float*)d_in[17];
  const float* ln2_b = (const float*)d_in[18];
  const float* w1 = (const float*)d_in[19];
  const float* b1 = (const float*)d_in[20];
  const float* w2 = (const float*)d_in[21];
  const float* b2 = (const float*)d_in[22];
  const float* lnf_g = (const float*)d_in[23];
  const float* lnf_b = (const float*)d_in[24];
  const float* logit_scale = (const float*)d_in[25];

  float* logits = (float*)d_out;                       // [R, V]
  float* states = logits + (size_t)Rc * Vc;            // [L, B, M, M]

  float* ws = (float*)d_ws;
  float* x = ws;                       // [R, D]
  float* xn = x + (size_t)Rc * Dc;     // [R, D]
  float* h1 = xn + (size_t)Rc * Dc;    // [R, 4D]
  float* kb = h1 + (size_t)Rc * Hc;    // [R, M]
  float* qb = kb + (size_t)Rc * Mc;
  float* vb = qb + (size_t)Rc * Mc;
  float* rd = vb + (size_t)Rc * Mc;
  float* gwb = rd + (size_t)Rc * Mc;   // [R]
  float* gfb = gwb + Rc;               // [R]

  gather_k<<<Rc, 128, 0, stream>>>(idx, center, x);

  for (int l = 0; l < Lc; ++l) {
    ln_k<<<Rc, 64, 0, stream>>>(x, ln1_g + (size_t)l * Dc, ln1_b + (size_t)l * Dc, xn);

    dim3 gKQV(Mc / 64, Rc / 64);
    gemm_nt<ACT_NONE, false, false><<<gKQV, 256, 0, stream>>>(
        xn, wk + (size_t)l * Mc * Dc, kb, bk + (size_t)l * Mc, Dc, Mc, nullptr, 1.f);
    gemm_nt<ACT_NONE, false, false><<<gKQV, 256, 0, stream>>>(
        xn, wq + (size_t)l * Mc * Dc, qb, bq + (size_t)l * Mc, Dc, Mc, nullptr, 1.f);
    gemm_nt<ACT_TANH, false, false><<<gKQV, 256, 0, stream>>>(
        xn, wv + (size_t)l * Mc * Dc, vb, bv + (size_t)l * Mc, Dc, Mc, nullptr, 1.f);
    l2n_k<<<Rc, 64, 0, stream>>>(kb);
    l2n_k<<<Rc, 64, 0, stream>>>(qb);
    gwgf_k<<<Rc, 64, 0, stream>>>(xn, wgw + (size_t)l * Dc, bgw + l,
                                  wgf + (size_t)l * Dc, bgf + l, gwb, gfb);

    scan_k<<<Bc, 256, 0, stream>>>(kb, qb, vb, gwb, gfb, rd,
                                   states + (size_t)l * Bc * Mc * Mc);

    // x += reads @ wo^T + bo
    dim3 gMO(Dc / 64, Rc / 64);
    gemm_nt<ACT_NONE, true, false><<<gMO, 256, 0, stream>>>(
        rd, wo + (size_t)l * Dc * Mc, x, bo + (size_t)l * Dc, Mc, Dc, nullptr, 1.f);

    ln_k<<<Rc, 64, 0, stream>>>(x, ln2_g + (size_t)l * Dc, ln2_b + (size_t)l * Dc, xn);

    dim3 gM1(Hc / 64, Rc / 64);
    gemm_nt<ACT_GELU, false, false><<<gM1, 256, 0, stream>>>(
        xn, w1 + (size_t)l * Hc * Dc, h1, b1 + (size_t)l * Hc, Dc, Hc, nullptr, 1.f);
    dim3 gM2(Dc / 64, Rc / 64);
    gemm_nt<ACT_NONE, true, false><<<gM2, 256, 0, stream>>>(
        h1, w2 + (size_t)l * Dc * Hc, x, b2 + (size_t)l * Dc, Hc, Dc, nullptr, 1.f);
  }

  ln_k<<<Rc, 64, 0, stream>>>(x, lnf_g, lnf_b, xn);

  dim3 gLG(Vc / 64, Rc / 64);
  gemm_nt<ACT_NONE, false, true><<<gLG, 256, 0, stream>>>(
      xn, center, logits, nullptr, Dc, Vc, logit_scale, 0.044194173824159223f);
}

// Round 2
// 898.133 us; speedup vs baseline: 3.7323x; 3.7323x over previous
//
#include <hip/hip_runtime.h>
#include <math.h>

// Problem constants
constexpr int Bc = 8, Tc = 256, Dc = 512, Mc = 128, Lc = 4, Vc = 32000;
constexpr int Rc = Bc * Tc;          // 2048 rows
constexpr int Hc = 4 * Dc;           // 2048 hidden

typedef __bf16 bf16_t;
typedef __bf16 bf16x8 __attribute__((ext_vector_type(8)));
typedef float f32x4 __attribute__((ext_vector_type(4)));
static_assert(sizeof(bf16x8) == 16, "bf16x8 must be 16B");

#define DEV __device__ __forceinline__

DEV float wred64(float x) {
#pragma unroll
  for (int o = 32; o; o >>= 1) x += __shfl_xor(x, o);
  return x;
}

// ---------------------------------------------------------------- fp32 -> bf16 convert
__global__ __launch_bounds__(256) void cvt_k(const float* __restrict__ in,
                                             bf16_t* __restrict__ out, int n) {
  int i = (blockIdx.x * 256 + threadIdx.x) * 8;
  if (i >= n) return;
  float4 a = *(const float4*)(in + i);
  float4 b = *(const float4*)(in + i + 4);
  bf16_t o[8] = {(bf16_t)a.x, (bf16_t)a.y, (bf16_t)a.z, (bf16_t)a.w,
                 (bf16_t)b.x, (bf16_t)b.y, (bf16_t)b.z, (bf16_t)b.w};
  *(bf16x8*)(out + i) = *(bf16x8*)o;
}

// pack wk|wq|wv -> [L][384][512] bf16
__global__ __launch_bounds__(128) void packkqv_k(const float* __restrict__ wk,
                                                 const float* __restrict__ wq,
                                                 const float* __restrict__ wv,
                                                 bf16_t* __restrict__ out) {
  int row = blockIdx.x;               // 0 .. L*384-1
  int lyr = row / 384, o = row % 384;
  const float* src = (o < 128) ? wk + ((size_t)lyr * 128 + o) * Dc
                   : (o < 256) ? wq + ((size_t)lyr * 128 + (o - 128)) * Dc
                               : wv + ((size_t)lyr * 128 + (o - 256)) * Dc;
  int t = threadIdx.x;
  float4 v = ((const float4*)src)[t];
  bf16_t* dst = out + (size_t)row * Dc + t * 4;
  dst[0] = (bf16_t)v.x; dst[1] = (bf16_t)v.y; dst[2] = (bf16_t)v.z; dst[3] = (bf16_t)v.w;
}

__global__ __launch_bounds__(256) void packb_k(const float* __restrict__ bk,
                                               const float* __restrict__ bq,
                                               const float* __restrict__ bv,
                                               float* __restrict__ out) {
  int i = blockIdx.x * 256 + threadIdx.x;
  if (i >= Lc * 384) return;
  int lyr = i / 384, o = i % 384;
  out[i] = (o < 128) ? bk[lyr * 128 + o] : (o < 256) ? bq[lyr * 128 + o - 128]
                                                     : bv[lyr * 128 + o - 256];
}

// ---------------------------------------------------------------- gather: x = center[idx]
__global__ __launch_bounds__(128) void gather_k(const int* __restrict__ idx,
                                                const float* __restrict__ center,
                                                float* __restrict__ x) {
  int r = blockIdx.x, t = threadIdx.x;
  int id = idx[r];
  ((float4*)(x + (size_t)r * Dc))[t] = ((const float4*)(center + (size_t)id * Dc))[t];
}

// ---------------------------------------------------------------- LayerNorm -> bf16
__global__ __launch_bounds__(64) void ln_k(const float* __restrict__ in,
                                           const float* __restrict__ g,
                                           const float* __restrict__ b,
                                           bf16_t* __restrict__ out) {
  int r = blockIdx.x, t = threadIdx.x;
  const float4* row = (const float4*)(in + (size_t)r * Dc);
  float xv[8];
  *(float4*)&xv[0] = row[2 * t];
  *(float4*)&xv[4] = row[2 * t + 1];
  float s = 0.f, ss = 0.f;
#pragma unroll
  for (int e = 0; e < 8; ++e) { s += xv[e]; ss += xv[e] * xv[e]; }
  s = wred64(s); ss = wred64(ss);
  float mu = s * (1.f / Dc);
  float var = ss * (1.f / Dc) - mu * mu;
  float inv = 1.f / sqrtf(var + 1e-5f);
  float gg[8], bb[8];
  *(float4*)&gg[0] = ((const float4*)g)[2 * t];
  *(float4*)&gg[4] = ((const float4*)g)[2 * t + 1];
  *(float4*)&bb[0] = ((const float4*)b)[2 * t];
  *(float4*)&bb[4] = ((const float4*)b)[2 * t + 1];
  bf16_t ob[8];
#pragma unroll
  for (int e = 0; e < 8; ++e) ob[e] = (bf16_t)((xv[e] - mu) * inv * gg[e] + bb[e]);
  *(bf16x8*)(out + (size_t)r * Dc + t * 8) = *(bf16x8*)ob;
}

// ---------------------------------------------------------------- gw/gf GEMV + sigmoid (bf16 xn)
__global__ __launch_bounds__(64) void gwgf_k(const bf16_t* __restrict__ xn,
                                             const float* __restrict__ wgw, const float* __restrict__ bgw,
                                             const float* __restrict__ wgf, const float* __restrict__ bgf,
                                             float* __restrict__ gw, float* __restrict__ gf) {
  int r = blockIdx.x, t = threadIdx.x;
  bf16x8 xv = *(const bf16x8*)(xn + (size_t)r * Dc + t * 8);
  float wa[8], wb[8];
  *(float4*)&wa[0] = ((const float4*)wgw)[2 * t];
  *(float4*)&wa[4] = ((const float4*)wgw)[2 * t + 1];
  *(float4*)&wb[0] = ((const float4*)wgf)[2 * t];
  *(float4*)&wb[4] = ((const float4*)wgf)[2 * t + 1];
  float dw = 0.f, df = 0.f;
#pragma unroll
  for (int e = 0; e < 8; ++e) {
    float xx = (float)xv[e];
    dw = fmaf(xx, wa[e], dw);
    df = fmaf(xx, wb[e], df);
  }
  dw = wred64(dw); df = wred64(df);
  if (t == 0) {
    gw[r] = 1.f / (1.f + expf(-(dw + bgw[0])));
    gf[r] = 0.9f / (1.f + expf(-(df + bgf[0])));
  }
}

// ---------------------------------------------------------------- l2norm k,q -> bf16 (+ reciprocal k-norm)
__global__ __launch_bounds__(64) void l2n_k(const float* __restrict__ kqv,
                                            bf16_t* __restrict__ kb, bf16_t* __restrict__ qb,
                                            float* __restrict__ rk) {
  int r = blockIdx.x, t = threadIdx.x;
  const float* row = kqv + (size_t)r * 384;
  float k0 = row[t], k1 = row[64 + t], q0 = row[128 + t], q1 = row[192 + t];
  float skk = wred64(k0 * k0 + k1 * k1);
  float sqq = wred64(q0 * q0 + q1 * q1);
  float rnk = 1.f / fmaxf(sqrtf(skk), 1e-12f);
  float rnq = 1.f / fmaxf(sqrtf(sqq), 1e-12f);
  kb[(size_t)r * 128 + t] = (bf16_t)(k0 * rnk);
  kb[(size_t)r * 128 + 64 + t] = (bf16_t)(k1 * rnk);
  qb[(size_t)r * 128 + t] = (bf16_t)(q0 * rnq);
  qb[(size_t)r * 128 + 64 + t] = (bf16_t)(q1 * rnq);
  if (t == 0) rk[r] = rnk;
}

// ---------------------------------------------------------------- per-batch decay prefix sums
// c[t] = sum_{u<=t} log gf_u ; wgt[s] = gw_s * exp(c[T-1]-c[s])
__global__ __launch_bounds__(256) void prefix_k(const float* __restrict__ gf,
                                                const float* __restrict__ gw,
                                                float* __restrict__ c, float* __restrict__ wgt) {
  int b = blockIdx.x, t = threadIdx.x, r = b * Tc + t;
  __shared__ float s[Tc];
  s[t] = logf(gf[r]);
  __syncthreads();
  for (int o = 1; o < Tc; o <<= 1) {
    float v = (t >= o) ? s[t - o] : 0.f;
    __syncthreads();
    s[t] += v;
    __syncthreads();
  }
  float ct = s[t];
  c[r] = ct;
  wgt[r] = gw[r] * expf(s[Tc - 1] - ct);
}

// ---------------------------------------------------------------- transpose 256xD slice -> bf16 [128][256]
template <int NOUT>
__global__ __launch_bounds__(256) void trans_k(const float* __restrict__ in, int ld, int coloff,
                                               const float* __restrict__ sc0,
                                               const float* __restrict__ sc1,
                                               bf16_t* __restrict__ out0,
                                               bf16_t* __restrict__ out1) {
  __shared__ float tile[64][65];
  int b = blockIdx.z, s0 = blockIdx.x * 64, d0 = blockIdx.y * 64, t = threadIdx.x;
#pragma unroll
  for (int i = 0; i < 4; ++i) {
    int cc = t + i * 256;
    int sl = cc >> 4, d4 = (cc & 15) * 4;
    float4 v = *(const float4*)(in + (size_t)(b * Tc + s0 + sl) * ld + coloff + d0 + d4);
    tile[sl][d4] = v.x; tile[sl][d4 + 1] = v.y; tile[sl][d4 + 2] = v.z; tile[sl][d4 + 3] = v.w;
  }
  __syncthreads();
#pragma unroll
  for (int i = 0; i < 2; ++i) {
    int cc = t + i * 256;
    int dl = cc >> 3, s8 = (cc & 7) * 8;
    bf16_t o0[8], o1[8];
#pragma unroll
    for (int e = 0; e < 8; ++e) {
      int s = s0 + s8 + e;
      float v = tile[s8 + e][dl];
      float f0 = sc0 ? sc0[b * Tc + s] : 1.f;
      o0[e] = (bf16_t)(v * f0);
      if (NOUT == 2) o1[e] = (bf16_t)(v * sc1[b * Tc + s]);
    }
    size_t oo = ((size_t)b * 128 + d0 + dl) * Tc + s0 + s8;
    *(bf16x8*)(out0 + oo) = *(bf16x8*)o0;
    if (NOUT == 2) *(bf16x8*)(out1 + oo) = *(bf16x8*)o1;
  }
}

// ---------------------------------------------------------------- bf16 MFMA GEMM (NT): C = epi(A@B^T)
// A [M,K] bf16 row-major, B [N,K] bf16 row-major. Tile 128x128, BK=64, 4 waves.
// LDS XOR-swizzle: byte ^= (row&7)<<4, applied on the global source (linear LDS dest,
// global_load_lds width 16) and on the ds_read address (both-sides rule, m201/m231).
enum { A_NONE = 0, A_KQV = 1, A_GELU = 2, A_PMASK = 3 };

DEV int swz_eoff(int row, int kbyte) {
  return row * 64 + ((kbyte ^ ((row & 7) << 4)) >> 1);
}

template <int ACT, bool ACCUM, bool SCALE, bool OBF16, bool SWZ>
__global__ __launch_bounds__(256, 2) void mm_k(
    const bf16_t* __restrict__ A, const bf16_t* __restrict__ B, void* __restrict__ Cv,
    const float* __restrict__ bias, int K, int lda, int ldb, int ldc,
    long long sA, long long sB, long long sC,
    const float* __restrict__ scale_ptr, float scale_const,
    const float* __restrict__ gwp, const float* __restrict__ cp) {
  __shared__ bf16_t As[128 * 64];
  __shared__ bf16_t Bs[128 * 64];
  const int z = blockIdx.z;
  int ntile, mtile;
  if (SWZ) {
    int nwg = gridDim.x * gridDim.y;           // must be %8==0 (logits: 4000)
    int orig = blockIdx.y * gridDim.x + blockIdx.x;
    int q = nwg >> 3;
    int id = (orig & 7) * q + (orig >> 3);     // bijective XCD chunking
    mtile = id % gridDim.y;
    ntile = id / gridDim.y;
  } else {
    ntile = blockIdx.x;
    mtile = blockIdx.y;
  }
  const int bm = mtile * 128, bn = ntile * 128;
  A += (size_t)z * sA;
  B += (size_t)z * sB;
  const int tid = threadIdx.x, w = tid >> 6, l = tid & 63;
  const int wm = (w >> 1) * 64, wn = (w & 1) * 64;
  const int l15 = l & 15, lhi = l >> 4;

  // staging chunks: 4 per thread per tile (1024 chunks of 16B = 128 rows x 128B)
  int rS[4], koS[4];
#pragma unroll
  for (int i = 0; i < 4; ++i) {
    int c = tid + i * 256;
    int r = c >> 3, kb = (c & 7) << 4;
    rS[i] = r;
    koS[i] = (kb ^ ((r & 7) << 4)) >> 1;   // element offset within row (inverse-swz source)
  }
  const bf16_t* Ab = A + (size_t)bm * lda;
  const bf16_t* Bb = B + (size_t)bn * ldb;

  f32x4 acc[4][4] = {};
  for (int k0 = 0; k0 < K; k0 += 64) {
#pragma unroll
    for (int i = 0; i < 4; ++i) {
      __builtin_amdgcn_global_load_lds(
          (const __attribute__((address_space(1))) void*)(Ab + (size_t)rS[i] * lda + k0 + koS[i]),
          (__attribute__((address_space(3))) void*)(As + ((size_t)w * 64 + i * 256) * 8), 16, 0, 0);
    }
#pragma unroll
    for (int i = 0; i < 4; ++i) {
      __builtin_amdgcn_global_load_lds(
          (const __attribute__((address_space(1))) void*)(Bb + (size_t)rS[i] * ldb + k0 + koS[i]),
          (__attribute__((address_space(3))) void*)(Bs + ((size_t)w * 64 + i * 256) * 8), 16, 0, 0);
    }
    __syncthreads();
    bf16x8 af[2][4], bf_[2][4];
#pragma unroll
    for (int h = 0; h < 2; ++h) {
#pragma unroll
      for (int m = 0; m < 4; ++m) {
        int row = wm + m * 16 + l15;
        af[h][m] = *(const bf16x8*)(As + swz_eoff(row, (h << 6) | (lhi << 4)));
        int col = wn + m * 16 + l15;
        bf_[h][m] = *(const bf16x8*)(Bs + swz_eoff(col, (h << 6) | (lhi << 4)));
      }
    }
#pragma unroll
    for (int h = 0; h < 2; ++h)
#pragma unroll
      for (int m = 0; m < 4; ++m)
#pragma unroll
        for (int n = 0; n < 4; ++n)
          acc[m][n] = __builtin_amdgcn_mfma_f32_16x16x32_bf16(af[h][m], bf_[h][n], acc[m][n], 0, 0, 0);
    __syncthreads();
  }

  float sc = 1.f;
  if (SCALE) sc = scale_const * scale_ptr[0];
  float* Cf = (float*)Cv;
  bf16_t* Cb = (bf16_t*)Cv;
#pragma unroll
  for (int m = 0; m < 4; ++m) {
#pragma unroll
    for (int n = 0; n < 4; ++n) {
#pragma unroll
      for (int q = 0; q < 4; ++q) {
        int row = bm + wm + m * 16 + lhi * 4 + q;   // C/D: col=lane&15, row=(lane>>4)*4+reg (m89)
        int col = bn + wn + n * 16 + l15;
        float val = acc[m][n][q];
        if (bias) val += bias[col];
        if (ACT == A_KQV) {
          if (col >= 256) val = tanhf(val);
        } else if (ACT == A_GELU) {
          val = 0.5f * val * (1.f + erff(val * 0.70710678118654752f));
        } else if (ACT == A_PMASK) {
          // P[t][s] = (s<t) ? gw_s * exp(c[t-1]-c[s]) * (q_t.k_s) : 0
          int t = row, s = col;
          if (s < t) val *= gwp[z * Tc + s] * expf(cp[z * Tc + t - 1] - cp[z * Tc + s]);
          else val = 0.f;
        }
        if (SCALE) val *= sc;
        size_t off = (size_t)z * sC + (size_t)row * ldc + col;
        if (OBF16) {
          Cb[off] = (bf16_t)val;
        } else {
          if (ACCUM) val += Cf[off];
          Cf[off] = val;
        }
      }
    }
  }
}

// ---------------------------------------------------------------- launcher
extern "C" void kernel_launch(void* const* d_in, const int* in_sizes, int n_in,
                              void* d_out, int out_size, void* d_ws, size_t ws_size,
                              hipStream_t stream) {
  const int* idx = (const int*)d_in[0];
  const float* center = (const float*)d_in[1];
  // d_in[2] offset: dead code (x = (b_min+b_max)/2 = center)
  const float* wk = (const float*)d_in[3];
  const float* bk = (const float*)d_in[4];
  const float* wq = (const float*)d_in[5];
  const float* bq = (const float*)d_in[6];
  const float* wv = (const float*)d_in[7];
  const float* bv = (const float*)d_in[8];
  const float* wo = (const float*)d_in[9];
  const float* bo = (const float*)d_in[10];
  const float* wgw = (const float*)d_in[11];
  const float* bgw = (const float*)d_in[12];
  const float* wgf = (const float*)d_in[13];
  const float* bgf = (const float*)d_in[14];
  const float* ln1_g = (const float*)d_in[15];
  const float* ln1_b = (const float*)d_in[16];
  const float* ln2_g = (const float*)d_in[17];
  const float* ln2_b = (const float*)d_in[18];
  const float* w1 = (const float*)d_in[19];
  const float* b1 = (const float*)d_in[20];
  const float* w2 = (const float*)d_in[21];
  const float* b2 = (const float*)d_in[22];
  const float* lnf_g = (const float*)d_in[23];
  const float* lnf_b = (const float*)d_in[24];
  const float* logit_scale = (const float*)d_in[25];

  float* logits = (float*)d_out;                     // [R, V] fp32
  float* states = logits + (size_t)Rc * Vc;          // [L, B, M, M] fp32

  char* p = (char*)d_ws;
  auto alloc = [&](size_t bytes) -> char* {
    char* r = p;
    p += (bytes + 255) & ~(size_t)255;
    return r;
  };
  float* x    = (float*)alloc((size_t)Rc * Dc * 4);
  float* kqv  = (float*)alloc((size_t)Rc * 384 * 4);
  float* gwb  = (float*)alloc(Rc * 4);
  float* gfb  = (float*)alloc(Rc * 4);
  float* cb   = (float*)alloc(Rc * 4);
  float* wgtb = (float*)alloc(Rc * 4);
  float* rkb  = (float*)alloc(Rc * 4);
  float* bkqv = (float*)alloc(Lc * 384 * 4);
  bf16_t* xn_bf   = (bf16_t*)alloc((size_t)Rc * Dc * 2);
  bf16_t* h1_bf   = (bf16_t*)alloc((size_t)Rc * Hc * 2);
  bf16_t* k_bf    = (bf16_t*)alloc((size_t)Rc * Mc * 2);
  bf16_t* q_bf    = (bf16_t*)alloc((size_t)Rc * Mc * 2);
  bf16_t* rd_bf   = (bf16_t*)alloc((size_t)Rc * Mc * 2);
  bf16_t* P_bf    = (bf16_t*)alloc((size_t)Bc * Tc * Tc * 2);
  bf16_t* kt_bf   = (bf16_t*)alloc((size_t)Bc * Mc * Tc * 2);
  bf16_t* vt_bf   = (bf16_t*)alloc((size_t)Bc * Mc * Tc * 2);
  bf16_t* vtw_bf  = (bf16_t*)alloc((size_t)Bc * Mc * Tc * 2);
  bf16_t* cen_bf  = (bf16_t*)alloc((size_t)Vc * Dc * 2);
  bf16_t* w1_bf   = (bf16_t*)alloc((size_t)Lc * Hc * Dc * 2);
  bf16_t* w2_bf   = (bf16_t*)alloc((size_t)Lc * Dc * Hc * 2);
  bf16_t* wo_bf   = (bf16_t*)alloc((size_t)Lc * Dc * Mc * 2);
  bf16_t* wkqv_bf = (bf16_t*)alloc((size_t)Lc * 384 * Dc * 2);

  auto cvt = [&](const float* src, bf16_t* dst, size_t n) {
    cvt_k<<<(unsigned)((n / 8 + 255) / 256), 256, 0, stream>>>(src, dst, (int)n);
  };
  cvt(center, cen_bf, (size_t)Vc * Dc);
  cvt(w1, w1_bf, (size_t)Lc * Hc * Dc);
  cvt(w2, w2_bf, (size_t)Lc * Dc * Hc);
  cvt(wo, wo_bf, (size_t)Lc * Dc * Mc);
  packkqv_k<<<Lc * 384, 128, 0, stream>>>(wk, wq, wv, wkqv_bf);
  packb_k<<<(Lc * 384 + 255) / 256, 256, 0, stream>>>(bk, bq, bv, bkqv);

  gather_k<<<Rc, 128, 0, stream>>>(idx, center, x);

  const long long zero = 0;
  for (int l = 0; l < Lc; ++l) {
    ln_k<<<Rc, 64, 0, stream>>>(x, ln1_g + (size_t)l * Dc, ln1_b + (size_t)l * Dc, xn_bf);

    // kqv = xn @ wkqv^T + b (tanh on v cols)
    mm_k<A_KQV, false, false, false, false><<<dim3(3, 16, 1), 256, 0, stream>>>(
        xn_bf, wkqv_bf + (size_t)l * 384 * Dc, kqv, bkqv + l * 384,
        Dc, Dc, Dc, 384, zero, zero, zero, nullptr, 1.f, nullptr, nullptr);

    l2n_k<<<Rc, 64, 0, stream>>>(kqv, k_bf, q_bf, rkb);
    gwgf_k<<<Rc, 64, 0, stream>>>(xn_bf, wgw + (size_t)l * Dc, bgw + l,
                                  wgf + (size_t)l * Dc, bgf + l, gwb, gfb);
    prefix_k<<<Bc, Tc, 0, stream>>>(gfb, gwb, cb, wgtb);

    // kt = (k/||k||)^T  [b][128][256] ; vt = v^T ; vtw = (wgt*v)^T
    trans_k<1><<<dim3(4, 2, Bc), 256, 0, stream>>>(kqv, 384, 0, rkb, nullptr, kt_bf, nullptr);
    trans_k<2><<<dim3(4, 2, Bc), 256, 0, stream>>>(kqv, 384, 256, nullptr, wgtb, vt_bf, vtw_bf);

    // P = mask_decay(q @ k^T)   [b][256][256] bf16
    mm_k<A_PMASK, false, false, true, false><<<dim3(2, 2, Bc), 256, 0, stream>>>(
        q_bf, k_bf, P_bf, nullptr, Mc, Mc, Mc, Tc,
        (long long)Tc * Mc, (long long)Tc * Mc, (long long)Tc * Tc,
        nullptr, 1.f, gwb, cb);

    // reads = P @ vt^T  -> bf16 [2048][128]
    mm_k<A_NONE, false, false, true, false><<<dim3(1, 2, Bc), 256, 0, stream>>>(
        P_bf, vt_bf, rd_bf, nullptr, Tc, Tc, Tc, Mc,
        (long long)Tc * Tc, (long long)Mc * Tc, (long long)Tc * Mc,
        nullptr, 1.f, nullptr, nullptr);

    // states = vtw @ kt^T -> fp32 direct to d_out
    mm_k<A_NONE, false, false, false, false><<<dim3(1, 1, Bc), 256, 0, stream>>>(
        vtw_bf, kt_bf, states + (size_t)l * Bc * Mc * Mc, nullptr, Tc, Tc, Tc, Mc,
        (long long)Mc * Tc, (long long)Mc * Tc, (long long)Mc * Mc,
        nullptr, 1.f, nullptr, nullptr);

    // x += reads @ wo^T + bo
    mm_k<A_NONE, true, false, false, false><<<dim3(4, 16, 1), 256, 0, stream>>>(
        rd_bf, wo_bf + (size_t)l * Dc * Mc, x, bo + (size_t)l * Dc,
        Mc, Mc, Mc, Dc, zero, zero, zero, nullptr, 1.f, nullptr, nullptr);

    ln_k<<<Rc, 64, 0, stream>>>(x, ln2_g + (size_t)l * Dc, ln2_b + (size_t)l * Dc, xn_bf);

    // h1 = gelu(xn @ w1^T + b1) -> bf16
    mm_k<A_GELU, false, false, true, false><<<dim3(16, 16, 1), 256, 0, stream>>>(
        xn_bf, w1_bf + (size_t)l * Hc * Dc, h1_bf, b1 + (size_t)l * Hc,
        Dc, Dc, Dc, Hc, zero, zero, zero, nullptr, 1.f, nullptr, nullptr);

    // x += h1 @ w2^T + b2
    mm_k<A_NONE, true, false, false, false><<<dim3(4, 16, 1), 256, 0, stream>>>(
        h1_bf, w2_bf + (size_t)l * Dc * Hc, x, b2 + (size_t)l * Dc,
        Hc, Hc, Hc, Dc, zero, zero, zero, nullptr, 1.f, nullptr, nullptr);
  }

  ln_k<<<Rc, 64, 0, stream>>>(x, lnf_g, lnf_b, xn_bf);

  // logits = (xn @ center^T) * logit_scale/sqrt(512)   (XCD-swizzled grid, 4000 blocks)
  mm_k<A_NONE, false, true, false, true><<<dim3(250, 16, 1), 256, 0, stream>>>(
      xn_bf, cen_bf, logits, nullptr, Dc, Dc, Dc, Vc, zero, zero, zero,
      logit_scale, 0.044194173824159223f, nullptr, nullptr);
}

// Round 3
// 752.193 us; speedup vs baseline: 4.4564x; 1.1940x over previous
//
#include <hip/hip_runtime.h>
#include <math.h>

// Problem constants
constexpr int Bc = 8, Tc = 256, Dc = 512, Mc = 128, Lc = 4, Vc = 32000;
constexpr int Rc = Bc * Tc;          // 2048 rows
constexpr int Hc = 4 * Dc;           // 2048 hidden

typedef __bf16 bf16_t;
typedef __bf16 bf16x8 __attribute__((ext_vector_type(8)));
typedef float f32x4 __attribute__((ext_vector_type(4)));
static_assert(sizeof(bf16x8) == 16, "bf16x8 must be 16B");

#define DEV __device__ __forceinline__

DEV float wred64(float x) {
#pragma unroll
  for (int o = 32; o; o >>= 1) x += __shfl_xor(x, o);
  return x;
}

// ---------------------------------------------------------------- fp32 -> bf16 convert
__global__ __launch_bounds__(256) void cvt_k(const float* __restrict__ in,
                                             bf16_t* __restrict__ out, int n) {
  int i = (blockIdx.x * 256 + threadIdx.x) * 8;
  if (i >= n) return;
  float4 a = *(const float4*)(in + i);
  float4 b = *(const float4*)(in + i + 4);
  bf16_t o[8] = {(bf16_t)a.x, (bf16_t)a.y, (bf16_t)a.z, (bf16_t)a.w,
                 (bf16_t)b.x, (bf16_t)b.y, (bf16_t)b.z, (bf16_t)b.w};
  *(bf16x8*)(out + i) = *(bf16x8*)o;
}

// pack wk|wq|wv|wgw|wgf|zeros -> [L][512][512] bf16 (gw/gf fused into kqv GEMM)
__global__ __launch_bounds__(128) void packkqv_k(const float* __restrict__ wk,
                                                 const float* __restrict__ wq,
                                                 const float* __restrict__ wv,
                                                 const float* __restrict__ wgw,
                                                 const float* __restrict__ wgf,
                                                 bf16_t* __restrict__ out) {
  int row = blockIdx.x;               // 0 .. L*512-1
  int lyr = row >> 9, o = row & 511;
  const float* src = nullptr;
  if (o < 128) src = wk + ((size_t)lyr * 128 + o) * Dc;
  else if (o < 256) src = wq + ((size_t)lyr * 128 + (o - 128)) * Dc;
  else if (o < 384) src = wv + ((size_t)lyr * 128 + (o - 256)) * Dc;
  else if (o == 384) src = wgw + (size_t)lyr * Dc;
  else if (o == 385) src = wgf + (size_t)lyr * Dc;
  int t = threadIdx.x;
  bf16_t* dst = out + (size_t)row * Dc + t * 4;
  if (src) {
    float4 v = ((const float4*)src)[t];
    dst[0] = (bf16_t)v.x; dst[1] = (bf16_t)v.y; dst[2] = (bf16_t)v.z; dst[3] = (bf16_t)v.w;
  } else {
    dst[0] = dst[1] = dst[2] = dst[3] = (bf16_t)0.f;
  }
}

__global__ __launch_bounds__(256) void packb_k(const float* __restrict__ bk,
                                               const float* __restrict__ bq,
                                               const float* __restrict__ bv,
                                               const float* __restrict__ bgw,
                                               const float* __restrict__ bgf,
                                               float* __restrict__ out) {
  int i = blockIdx.x * 256 + threadIdx.x;
  if (i >= Lc * 512) return;
  int lyr = i >> 9, o = i & 511;
  float v = 0.f;
  if (o < 128) v = bk[lyr * 128 + o];
  else if (o < 256) v = bq[lyr * 128 + o - 128];
  else if (o < 384) v = bv[lyr * 128 + o - 256];
  else if (o == 384) v = bgw[lyr];
  else if (o == 385) v = bgf[lyr];
  out[i] = v;
}

// ---------------------------------------------------------------- gather + first LN (fused)
__global__ __launch_bounds__(64) void gl_k(const int* __restrict__ idx,
                                           const float* __restrict__ center,
                                           const float* __restrict__ g,
                                           const float* __restrict__ b,
                                           float* __restrict__ x,
                                           bf16_t* __restrict__ xn) {
  int r = blockIdx.x, t = threadIdx.x;
  const float4* row = (const float4*)(center + (size_t)idx[r] * Dc);
  float xv[8];
  *(float4*)&xv[0] = row[2 * t];
  *(float4*)&xv[4] = row[2 * t + 1];
  float4* xrow = (float4*)(x + (size_t)r * Dc);
  xrow[2 * t] = *(float4*)&xv[0];
  xrow[2 * t + 1] = *(float4*)&xv[4];
  float s = 0.f, ss = 0.f;
#pragma unroll
  for (int e = 0; e < 8; ++e) { s += xv[e]; ss += xv[e] * xv[e]; }
  s = wred64(s); ss = wred64(ss);
  float mu = s * (1.f / Dc);
  float inv = 1.f / sqrtf(ss * (1.f / Dc) - mu * mu + 1e-5f);
  float gg[8], bb[8];
  *(float4*)&gg[0] = ((const float4*)g)[2 * t];
  *(float4*)&gg[4] = ((const float4*)g)[2 * t + 1];
  *(float4*)&bb[0] = ((const float4*)b)[2 * t];
  *(float4*)&bb[4] = ((const float4*)b)[2 * t + 1];
  bf16_t ob[8];
#pragma unroll
  for (int e = 0; e < 8; ++e) ob[e] = (bf16_t)((xv[e] - mu) * inv * gg[e] + bb[e]);
  *(bf16x8*)(xn + (size_t)r * Dc + t * 8) = *(bf16x8*)ob;
}

// ---------------------------------------------------------------- LayerNorm -> bf16 (used for ln2)
__global__ __launch_bounds__(64) void ln_k(const float* __restrict__ in,
                                           const float* __restrict__ g,
                                           const float* __restrict__ b,
                                           bf16_t* __restrict__ out) {
  int r = blockIdx.x, t = threadIdx.x;
  const float4* row = (const float4*)(in + (size_t)r * Dc);
  float xv[8];
  *(float4*)&xv[0] = row[2 * t];
  *(float4*)&xv[4] = row[2 * t + 1];
  float s = 0.f, ss = 0.f;
#pragma unroll
  for (int e = 0; e < 8; ++e) { s += xv[e]; ss += xv[e] * xv[e]; }
  s = wred64(s); ss = wred64(ss);
  float mu = s * (1.f / Dc);
  float inv = 1.f / sqrtf(ss * (1.f / Dc) - mu * mu + 1e-5f);
  float gg[8], bb[8];
  *(float4*)&gg[0] = ((const float4*)g)[2 * t];
  *(float4*)&gg[4] = ((const float4*)g)[2 * t + 1];
  *(float4*)&bb[0] = ((const float4*)b)[2 * t];
  *(float4*)&bb[4] = ((const float4*)b)[2 * t + 1];
  bf16_t ob[8];
#pragma unroll
  for (int e = 0; e < 8; ++e) ob[e] = (bf16_t)((xv[e] - mu) * inv * gg[e] + bb[e]);
  *(bf16x8*)(out + (size_t)r * Dc + t * 8) = *(bf16x8*)ob;
}

// ---------------------------------------------------------------- split-K reduce + bias + residual + LN
// x = x + part0 + part1 + bias; xn = LN(x, g, b)
__global__ __launch_bounds__(64) void redln_k(const float* __restrict__ part,
                                              const float* __restrict__ bias,
                                              float* __restrict__ x,
                                              const float* __restrict__ g,
                                              const float* __restrict__ b,
                                              bf16_t* __restrict__ xn) {
  int r = blockIdx.x, t = threadIdx.x;
  const float4* xr = (const float4*)(x + (size_t)r * Dc);
  const float4* p0 = (const float4*)(part + (size_t)r * Dc);
  const float4* p1 = (const float4*)(part + (size_t)(Rc + r) * Dc);
  const float4* bb4 = (const float4*)bias;
  float xv[8];
#pragma unroll
  for (int j = 0; j < 2; ++j) {
    float4 a = xr[2 * t + j], q = p0[2 * t + j], w = p1[2 * t + j], c = bb4[2 * t + j];
    xv[4 * j + 0] = a.x + q.x + w.x + c.x;
    xv[4 * j + 1] = a.y + q.y + w.y + c.y;
    xv[4 * j + 2] = a.z + q.z + w.z + c.z;
    xv[4 * j + 3] = a.w + q.w + w.w + c.w;
  }
  float4* xw = (float4*)(x + (size_t)r * Dc);
  xw[2 * t] = *(float4*)&xv[0];
  xw[2 * t + 1] = *(float4*)&xv[4];
  float s = 0.f, ss = 0.f;
#pragma unroll
  for (int e = 0; e < 8; ++e) { s += xv[e]; ss += xv[e] * xv[e]; }
  s = wred64(s); ss = wred64(ss);
  float mu = s * (1.f / Dc);
  float inv = 1.f / sqrtf(ss * (1.f / Dc) - mu * mu + 1e-5f);
  float gg[8], bv[8];
  *(float4*)&gg[0] = ((const float4*)g)[2 * t];
  *(float4*)&gg[4] = ((const float4*)g)[2 * t + 1];
  *(float4*)&bv[0] = ((const float4*)b)[2 * t];
  *(float4*)&bv[4] = ((const float4*)b)[2 * t + 1];
  bf16_t ob[8];
#pragma unroll
  for (int e = 0; e < 8; ++e) ob[e] = (bf16_t)((xv[e] - mu) * inv * gg[e] + bv[e]);
  *(bf16x8*)(xn + (size_t)r * Dc + t * 8) = *(bf16x8*)ob;
}

// ---------------------------------------------------------------- per-batch decay prefix sums
__global__ __launch_bounds__(256) void prefix_k(const float* __restrict__ gf,
                                                const float* __restrict__ gw,
                                                float* __restrict__ c, float* __restrict__ wgt) {
  int b = blockIdx.x, t = threadIdx.x, r = b * Tc + t;
  __shared__ float s[Tc];
  s[t] = logf(gf[r]);
  __syncthreads();
  for (int o = 1; o < Tc; o <<= 1) {
    float v = (t >= o) ? s[t - o] : 0.f;
    __syncthreads();
    s[t] += v;
    __syncthreads();
  }
  float ct = s[t];
  c[r] = ct;
  wgt[r] = gw[r] * expf(s[Tc - 1] - ct);
}

// ---------------------------------------------------------------- fused l2norm + transposes
// per block: 32 s-rows of one batch. Emits k_bf,q_bf (normalized, row-major [R][128])
// and kt (=k_norm^T), vt (=v^T), vtw (=(wgt*v)^T), each [B][128][256] bf16.
__global__ __launch_bounds__(256) void prep_k(const float* __restrict__ kqv,
                                              const float* __restrict__ wgt,
                                              bf16_t* __restrict__ kb, bf16_t* __restrict__ qb,
                                              bf16_t* __restrict__ kt, bf16_t* __restrict__ vt,
                                              bf16_t* __restrict__ vtw) {
  __shared__ float tile[32][385];   // +1 pad -> conflict-free column reads
  __shared__ float rnk[32], rnq[32], sw[32];
  int b = blockIdx.y, s0 = blockIdx.x * 32, t = threadIdx.x;
  const float* src = kqv + (size_t)(b * Tc + s0) * 384;
#pragma unroll
  for (int i = 0; i < 12; ++i) {
    int c = t + i * 256;
    int row = c / 96, c4 = (c % 96) * 4;
    float4 v = *(const float4*)(src + (size_t)row * 384 + c4);
    tile[row][c4] = v.x; tile[row][c4 + 1] = v.y; tile[row][c4 + 2] = v.z; tile[row][c4 + 3] = v.w;
  }
  if (t < 32) sw[t] = wgt[b * Tc + s0 + t];
  __syncthreads();
  {
    int row = t >> 3, sub = t & 7;
    float sk = 0.f, sq = 0.f;
#pragma unroll
    for (int e = 0; e < 16; ++e) {
      float a = tile[row][sub * 16 + e]; sk += a * a;
      float c = tile[row][128 + sub * 16 + e]; sq += c * c;
    }
#pragma unroll
    for (int o = 1; o < 8; o <<= 1) { sk += __shfl_xor(sk, o); sq += __shfl_xor(sq, o); }
    if (!sub) { rnk[row] = 1.f / fmaxf(sqrtf(sk), 1e-12f); rnq[row] = 1.f / fmaxf(sqrtf(sq), 1e-12f); }
  }
  __syncthreads();
  // row-major normalized k,q
#pragma unroll
  for (int i = 0; i < 2; ++i) {
    int c = t + i * 256;
    int row = c >> 4, e8 = (c & 15) * 8;
    float rk = rnk[row], rq = rnq[row];
    bf16_t ok[8], oq[8];
#pragma unroll
    for (int e = 0; e < 8; ++e) {
      ok[e] = (bf16_t)(tile[row][e8 + e] * rk);
      oq[e] = (bf16_t)(tile[row][128 + e8 + e] * rq);
    }
    size_t ro = (size_t)(b * Tc + s0 + row) * Mc + e8;
    *(bf16x8*)(kb + ro) = *(bf16x8*)ok;
    *(bf16x8*)(qb + ro) = *(bf16x8*)oq;
  }
  // transposed kt / vt / vtw
#pragma unroll
  for (int i = 0; i < 2; ++i) {
    int c = t + i * 256;
    int d = c >> 2, s8 = (c & 3) * 8;
    bf16_t a0[8], a1[8], a2[8];
#pragma unroll
    for (int e = 0; e < 8; ++e) {
      int s = s8 + e;
      a0[e] = (bf16_t)(tile[s][d] * rnk[s]);
      float v = tile[s][256 + d];
      a1[e] = (bf16_t)v;
      a2[e] = (bf16_t)(v * sw[s]);
    }
    size_t oo = ((size_t)b * Mc + d) * Tc + s0 + s8;
    *(bf16x8*)(kt + oo) = *(bf16x8*)a0;
    *(bf16x8*)(vt + oo) = *(bf16x8*)a1;
    *(bf16x8*)(vtw + oo) = *(bf16x8*)a2;
  }
}

// ---------------------------------------------------------------- bf16 MFMA GEMM (NT): C = epi(A@B^T)
// Tile 128x128, BK=64, 4 waves. LDS XOR-swizzle on both sides (m201/m231 rule).
enum { A_NONE = 0, A_KQV = 1, A_GELU = 2, A_PMASK = 3 };

DEV int swz_eoff(int row, int kbyte) {
  return row * 64 + ((kbyte ^ ((row & 7) << 4)) >> 1);
}

template <int ACT, bool ACCUM, bool SCALE, bool OBF16, bool SWZ>
__global__ __launch_bounds__(256, 3) void mm_k(
    const bf16_t* __restrict__ A, const bf16_t* __restrict__ B, void* __restrict__ Cv,
    const float* __restrict__ bias, int K, int lda, int ldb, int ldc,
    long long sA, long long sB, long long sC,
    const float* __restrict__ scale_ptr, float scale_const,
    const float* __restrict__ gwp, const float* __restrict__ cp,
    float* __restrict__ o0, float* __restrict__ o1) {
  __shared__ bf16_t As[128 * 64];
  __shared__ bf16_t Bs[128 * 64];
  const int z = blockIdx.z;
  int ntile, mtile;
  if (SWZ) {
    int nwg = gridDim.x * gridDim.y;           // must be %8==0 (logits: 4000)
    int orig = blockIdx.y * gridDim.x + blockIdx.x;
    int q = nwg >> 3;
    int id = (orig & 7) * q + (orig >> 3);     // bijective XCD chunking
    mtile = id % gridDim.y;
    ntile = id / gridDim.y;
  } else {
    ntile = blockIdx.x;
    mtile = blockIdx.y;
  }
  const int bm = mtile * 128, bn = ntile * 128;
  A += (size_t)z * sA;
  B += (size_t)z * sB;
  const int tid = threadIdx.x, w = tid >> 6, l = tid & 63;
  const int wm = (w >> 1) * 64, wn = (w & 1) * 64;
  const int l15 = l & 15, lhi = l >> 4;

  int rS[4], koS[4];
#pragma unroll
  for (int i = 0; i < 4; ++i) {
    int c = tid + i * 256;
    int r = c >> 3, kb = (c & 7) << 4;
    rS[i] = r;
    koS[i] = (kb ^ ((r & 7) << 4)) >> 1;   // inverse-swz source element offset
  }
  const bf16_t* Ab = A + (size_t)bm * lda;
  const bf16_t* Bb = B + (size_t)bn * ldb;

  f32x4 acc[4][4] = {};
  for (int k0 = 0; k0 < K; k0 += 64) {
#pragma unroll
    for (int i = 0; i < 4; ++i) {
      __builtin_amdgcn_global_load_lds(
          (const __attribute__((address_space(1))) void*)(Ab + (size_t)rS[i] * lda + k0 + koS[i]),
          (__attribute__((address_space(3))) void*)(As + ((size_t)w * 64 + i * 256) * 8), 16, 0, 0);
    }
#pragma unroll
    for (int i = 0; i < 4; ++i) {
      __builtin_amdgcn_global_load_lds(
          (const __attribute__((address_space(1))) void*)(Bb + (size_t)rS[i] * ldb + k0 + koS[i]),
          (__attribute__((address_space(3))) void*)(Bs + ((size_t)w * 64 + i * 256) * 8), 16, 0, 0);
    }
    __syncthreads();
    bf16x8 af[2][4], bf_[2][4];
#pragma unroll
    for (int h = 0; h < 2; ++h) {
#pragma unroll
      for (int m = 0; m < 4; ++m) {
        int row = wm + m * 16 + l15;
        af[h][m] = *(const bf16x8*)(As + swz_eoff(row, (h << 6) | (lhi << 4)));
        int col = wn + m * 16 + l15;
        bf_[h][m] = *(const bf16x8*)(Bs + swz_eoff(col, (h << 6) | (lhi << 4)));
      }
    }
#pragma unroll
    for (int h = 0; h < 2; ++h)
#pragma unroll
      for (int m = 0; m < 4; ++m)
#pragma unroll
        for (int n = 0; n < 4; ++n)
          acc[m][n] = __builtin_amdgcn_mfma_f32_16x16x32_bf16(af[h][m], bf_[h][n], acc[m][n], 0, 0, 0);
    __syncthreads();
  }

  float sc = 1.f;
  if (SCALE) sc = scale_const * scale_ptr[0];
  float* Cf = (float*)Cv;
  bf16_t* Cb = (bf16_t*)Cv;
#pragma unroll
  for (int m = 0; m < 4; ++m) {
#pragma unroll
    for (int n = 0; n < 4; ++n) {
#pragma unroll
      for (int q = 0; q < 4; ++q) {
        int row = bm + wm + m * 16 + lhi * 4 + q;   // C/D: col=lane&15, row=(lane>>4)*4+reg (m89)
        int col = bn + wn + n * 16 + l15;
        float val = acc[m][n][q];
        if (bias) val += bias[col];
        if (ACT == A_KQV) {
          // cols [0,256): k,q raw; [256,384): tanh (v); 384: gw=sigmoid; 385: gf=0.9*sigmoid; rest drop
          if (col < 256) {
            Cf[(size_t)row * ldc + col] = val;
          } else if (col < 384) {
            Cf[(size_t)row * ldc + col] = tanhf(val);
          } else if (col == 384) {
            o0[row] = 1.f / (1.f + expf(-val));
          } else if (col == 385) {
            o1[row] = 0.9f / (1.f + expf(-val));
          }
          continue;
        }
        if (ACT == A_GELU) {
          val = 0.5f * val * (1.f + erff(val * 0.70710678118654752f));
        } else if (ACT == A_PMASK) {
          int t = row, s = col;
          if (s < t) val *= gwp[z * Tc + s] * expf(cp[z * Tc + t - 1] - cp[z * Tc + s]);
          else val = 0.f;
        }
        if (SCALE) val *= sc;
        size_t off = (size_t)z * sC + (size_t)row * ldc + col;
        if (OBF16) {
          Cb[off] = (bf16_t)val;
        } else {
          if (ACCUM) val += Cf[off];
          Cf[off] = val;
        }
      }
    }
  }
}

// ---------------------------------------------------------------- launcher
extern "C" void kernel_launch(void* const* d_in, const int* in_sizes, int n_in,
                              void* d_out, int out_size, void* d_ws, size_t ws_size,
                              hipStream_t stream) {
  const int* idx = (const int*)d_in[0];
  const float* center = (const float*)d_in[1];
  // d_in[2] offset: dead code (x = (b_min+b_max)/2 = center)
  const float* wk = (const float*)d_in[3];
  const float* bk = (const float*)d_in[4];
  const float* wq = (const float*)d_in[5];
  const float* bq = (const float*)d_in[6];
  const float* wv = (const float*)d_in[7];
  const float* bv = (const float*)d_in[8];
  const float* wo = (const float*)d_in[9];
  const float* bo = (const float*)d_in[10];
  const float* wgw = (const float*)d_in[11];
  const float* bgw = (const float*)d_in[12];
  const float* wgf = (const float*)d_in[13];
  const float* bgf = (const float*)d_in[14];
  const float* ln1_g = (const float*)d_in[15];
  const float* ln1_b = (const float*)d_in[16];
  const float* ln2_g = (const float*)d_in[17];
  const float* ln2_b = (const float*)d_in[18];
  const float* w1 = (const float*)d_in[19];
  const float* b1 = (const float*)d_in[20];
  const float* w2 = (const float*)d_in[21];
  const float* b2 = (const float*)d_in[22];
  const float* lnf_g = (const float*)d_in[23];
  const float* lnf_b = (const float*)d_in[24];
  const float* logit_scale = (const float*)d_in[25];

  float* logits = (float*)d_out;                     // [R, V] fp32
  float* states = logits + (size_t)Rc * Vc;          // [L, B, M, M] fp32

  char* p = (char*)d_ws;
  auto alloc = [&](size_t bytes) -> char* {
    char* r = p;
    p += (bytes + 255) & ~(size_t)255;
    return r;
  };
  float* x    = (float*)alloc((size_t)Rc * Dc * 4);
  float* kqv  = (float*)alloc((size_t)Rc * 384 * 4);
  float* gwb  = (float*)alloc(Rc * 4);
  float* gfb  = (float*)alloc(Rc * 4);
  float* cb   = (float*)alloc(Rc * 4);
  float* wgtb = (float*)alloc(Rc * 4);
  float* bkqv = (float*)alloc(Lc * 512 * 4);
  float* part = (float*)alloc((size_t)2 * Rc * Dc * 4);   // split-K partials for w2
  bf16_t* xn_bf   = (bf16_t*)alloc((size_t)Rc * Dc * 2);
  bf16_t* h1_bf   = (bf16_t*)alloc((size_t)Rc * Hc * 2);
  bf16_t* k_bf    = (bf16_t*)alloc((size_t)Rc * Mc * 2);
  bf16_t* q_bf    = (bf16_t*)alloc((size_t)Rc * Mc * 2);
  bf16_t* rd_bf   = (bf16_t*)alloc((size_t)Rc * Mc * 2);
  bf16_t* P_bf    = (bf16_t*)alloc((size_t)Bc * Tc * Tc * 2);
  bf16_t* kt_bf   = (bf16_t*)alloc((size_t)Bc * Mc * Tc * 2);
  bf16_t* vt_bf   = (bf16_t*)alloc((size_t)Bc * Mc * Tc * 2);
  bf16_t* vtw_bf  = (bf16_t*)alloc((size_t)Bc * Mc * Tc * 2);
  bf16_t* cen_bf  = (bf16_t*)alloc((size_t)Vc * Dc * 2);
  bf16_t* w1_bf   = (bf16_t*)alloc((size_t)Lc * Hc * Dc * 2);
  bf16_t* w2_bf   = (bf16_t*)alloc((size_t)Lc * Dc * Hc * 2);
  bf16_t* wo_bf   = (bf16_t*)alloc((size_t)Lc * Dc * Mc * 2);
  bf16_t* wkqv_bf = (bf16_t*)alloc((size_t)Lc * 512 * Dc * 2);

  auto cvt = [&](const float* src, bf16_t* dst, size_t n) {
    cvt_k<<<(unsigned)((n / 8 + 255) / 256), 256, 0, stream>>>(src, dst, (int)n);
  };
  cvt(center, cen_bf, (size_t)Vc * Dc);
  cvt(w1, w1_bf, (size_t)Lc * Hc * Dc);
  cvt(w2, w2_bf, (size_t)Lc * Dc * Hc);
  cvt(wo, wo_bf, (size_t)Lc * Dc * Mc);
  packkqv_k<<<Lc * 512, 128, 0, stream>>>(wk, wq, wv, wgw, wgf, wkqv_bf);
  packb_k<<<(Lc * 512 + 255) / 256, 256, 0, stream>>>(bk, bq, bv, bgw, bgf, bkqv);

  // gather + ln1(layer 0) fused
  gl_k<<<Rc, 64, 0, stream>>>(idx, center, ln1_g, ln1_b, x, xn_bf);

  const long long zero = 0;
  for (int l = 0; l < Lc; ++l) {
    // kqv+gw+gf = xn @ [wk;wq;wv;wgw;wgf]^T + b  (tanh on v, sigmoid on gw/gf)
    mm_k<A_KQV, false, false, false, false><<<dim3(4, 16, 1), 256, 0, stream>>>(
        xn_bf, wkqv_bf + (size_t)l * 512 * Dc, kqv, bkqv + l * 512,
        Dc, Dc, Dc, 384, zero, zero, zero, nullptr, 1.f, nullptr, nullptr, gwb, gfb);

    prefix_k<<<Bc, Tc, 0, stream>>>(gfb, gwb, cb, wgtb);

    // fused l2norm + transposes
    prep_k<<<dim3(Tc / 32, Bc), 256, 0, stream>>>(kqv, wgtb, k_bf, q_bf, kt_bf, vt_bf, vtw_bf);

    // P = mask_decay(q @ k^T)
    mm_k<A_PMASK, false, false, true, false><<<dim3(2, 2, Bc), 256, 0, stream>>>(
        q_bf, k_bf, P_bf, nullptr, Mc, Mc, Mc, Tc,
        (long long)Tc * Mc, (long long)Tc * Mc, (long long)Tc * Tc,
        nullptr, 1.f, gwb, cb, nullptr, nullptr);

    // reads = P @ vt^T
    mm_k<A_NONE, false, false, true, false><<<dim3(1, 2, Bc), 256, 0, stream>>>(
        P_bf, vt_bf, rd_bf, nullptr, Tc, Tc, Tc, Mc,
        (long long)Tc * Tc, (long long)Mc * Tc, (long long)Tc * Mc,
        nullptr, 1.f, nullptr, nullptr, nullptr, nullptr);

    // states = vtw @ kt^T -> fp32 direct to d_out
    mm_k<A_NONE, false, false, false, false><<<dim3(1, 1, Bc), 256, 0, stream>>>(
        vtw_bf, kt_bf, states + (size_t)l * Bc * Mc * Mc, nullptr, Tc, Tc, Tc, Mc,
        (long long)Mc * Tc, (long long)Mc * Tc, (long long)Mc * Mc,
        nullptr, 1.f, nullptr, nullptr, nullptr, nullptr);

    // x += reads @ wo^T + bo
    mm_k<A_NONE, true, false, false, false><<<dim3(4, 16, 1), 256, 0, stream>>>(
        rd_bf, wo_bf + (size_t)l * Dc * Mc, x, bo + (size_t)l * Dc,
        Mc, Mc, Mc, Dc, zero, zero, zero, nullptr, 1.f, nullptr, nullptr, nullptr, nullptr);

    ln_k<<<Rc, 64, 0, stream>>>(x, ln2_g + (size_t)l * Dc, ln2_b + (size_t)l * Dc, xn_bf);

    // h1 = gelu(xn @ w1^T + b1) -> bf16
    mm_k<A_GELU, false, false, true, false><<<dim3(16, 16, 1), 256, 0, stream>>>(
        xn_bf, w1_bf + (size_t)l * Hc * Dc, h1_bf, b1 + (size_t)l * Hc,
        Dc, Dc, Dc, Hc, zero, zero, zero, nullptr, 1.f, nullptr, nullptr, nullptr, nullptr);

    // w2 split-K=2: partials (z strides slice A/B along K)
    mm_k<A_NONE, false, false, false, false><<<dim3(4, 16, 2), 256, 0, stream>>>(
        h1_bf, w2_bf + (size_t)l * Dc * Hc, part, nullptr,
        Hc / 2, Hc, Hc, Dc, (long long)(Hc / 2), (long long)(Hc / 2), (long long)Rc * Dc,
        nullptr, 1.f, nullptr, nullptr, nullptr, nullptr);

    // x += partials + b2 ; xn = LN(x) with next layer's ln1 (or lnf after last layer)
    const float* ng = (l < Lc - 1) ? ln1_g + (size_t)(l + 1) * Dc : lnf_g;
    const float* nb = (l < Lc - 1) ? ln1_b + (size_t)(l + 1) * Dc : lnf_b;
    redln_k<<<Rc, 64, 0, stream>>>(part, b2 + (size_t)l * Dc, x, ng, nb, xn_bf);
  }

  // logits = (xn @ center^T) * logit_scale/sqrt(512)   (XCD-swizzled, 4000 blocks)
  mm_k<A_NONE, false, true, false, true><<<dim3(250, 16, 1), 256, 0, stream>>>(
      xn_bf, cen_bf, logits, nullptr, Dc, Dc, Dc, Vc, zero, zero, zero,
      logit_scale, 0.044194173824159223f, nullptr, nullptr, nullptr, nullptr);
}